// Round 2
// baseline (1358.495 us; speedup 1.0000x reference)
//
#include <hip/hip_runtime.h>
#include <hip/hip_bf16.h>
#include <stdint.h>

// LSTM cell, B=8192, IN=H=2048. Fused GEMM: M=8192, N=8192 (4 gates x 2048), K=4096.
// I/O is fp32 (reference dtype); internal compute bf16 MFMA (threshold is bf16-floor).
// A (x|h) staged fp32 -> LDS via global_load_lds, converted at fragment read.
// W transposed+converted once into ws as bf16 Wt[n][k] (64 MB).

typedef short bf16x8 __attribute__((ext_vector_type(8)));
typedef float f32x4 __attribute__((ext_vector_type(4)));

typedef const __attribute__((address_space(1))) void* gptr_as1;
typedef __attribute__((address_space(3))) void* lptr_as3;

__device__ __forceinline__ void g2lds16(const void* g, void* l) {
  // async global->LDS, 16B/lane; LDS dst = wave-uniform base + lane*16 (m97/m104 pattern)
  __builtin_amdgcn_global_load_lds((gptr_as1)g, (lptr_as3)l, 16, 0, 0);
}

__device__ __forceinline__ short f2bs(float x) {
  __hip_bfloat16 h = __float2bfloat16(x);  // RNE
  return *reinterpret_cast<short*>(&h);
}

// ---------------------------------------------------------------------------
// Transpose + convert fused weights: Wt[n][k] bf16, n in [0,8192) gate-major
// [f,i,g,o], k in [0,4096): k<2048 from W_i[k][n] (fp32), else W_h[k-2048][n].
// ---------------------------------------------------------------------------
__global__ void transpose_w(const float* __restrict__ Wi,
                            const float* __restrict__ Wh,
                            __hip_bfloat16* __restrict__ Wt) {
  __shared__ float tile[32][33];
  const int nt = blockIdx.x * 32;   // 256 blocks
  const int kt = blockIdx.y * 32;   // 128 blocks
  const float* src = (kt < 2048) ? (Wi + (size_t)kt * 8192)
                                 : (Wh + (size_t)(kt - 2048) * 8192);
  for (int i = threadIdx.y; i < 32; i += 8)
    tile[i][threadIdx.x] = src[(size_t)i * 8192 + nt + threadIdx.x];
  __syncthreads();
  for (int i = threadIdx.y; i < 32; i += 8)
    Wt[(size_t)(nt + i) * 4096 + kt + threadIdx.x] = __float2bfloat16(tile[threadIdx.x][i]);
}

// ---------------------------------------------------------------------------
// Fused GEMM + LSTM epilogue. Block tile: 128 rows x (32 j x 4 gates).
// Wave grid 2x2; wave = 64 rows x 16 j x 4 gates; gate = MFMA tile column ->
// all 4 gates of (m,j) in same lane/regs -> in-register epilogue.
// LDS: As fp32 [128][32] (16KB, XOR-swizzled chunks), Bs bf16 [128][32] (8KB, swizzled).
// ---------------------------------------------------------------------------
__global__ __launch_bounds__(256) void lstm_fused(
    const float* __restrict__ X,              // [8192][2048]
    const float* __restrict__ Hp,             // [8192][2048]
    const float* __restrict__ Cp,             // [8192][2048]
    const __hip_bfloat16* __restrict__ Wt,    // [8192][4096] bf16
    const float* __restrict__ bi,             // [8192]
    const float* __restrict__ bh,             // [8192]
    float* __restrict__ out)                  // [3][8192][2048]
{
  __shared__ __align__(16) float As[4096];            // [128 rows][8 chunks of 4 fp32]
  __shared__ __align__(16) __hip_bfloat16 Bs[4096];   // [128 rows][4 chunks of 8 bf16]
  const int t  = threadIdx.x;
  const int m0 = blockIdx.x * 128;
  const int j0 = blockIdx.y * 32;

  // --- staging plan ---
  // As: 1024 chunks (16B = 4 fp32). chunk c: row=c>>3, pos=c&7 holds global
  // k-chunk q_g = pos ^ (row&7)  (bank-conflict swizzle; dst stays lane-contiguous).
  const float* gax[4];
  const float* gah[4];
  float* la[4];
#pragma unroll
  for (int i = 0; i < 4; ++i) {
    const int c = i * 256 + t;
    const int row = c >> 3, pos = c & 7;
    const int qg = pos ^ (row & 7);
    gax[i] = X  + (size_t)(m0 + row) * 2048 + qg * 4;
    gah[i] = Hp + (size_t)(m0 + row) * 2048 + qg * 4;
    la[i]  = As + c * 4;
  }
  // Bs: 512 chunks (16B = 8 bf16). chunk c: row=c>>2 (gathered col, gate-major),
  // pos=c&3 holds global k-chunk q_g = pos ^ ((row>>1)&3).
  const __hip_bfloat16* gb[2];
  __hip_bfloat16* lb[2];
#pragma unroll
  for (int i = 0; i < 2; ++i) {
    const int c = i * 256 + t;
    const int row = c >> 2, pos = c & 3;
    const int qg = pos ^ ((row >> 1) & 3);
    const int n = (row >> 5) * 2048 + j0 + (row & 31);  // gate-major W column
    gb[i] = Wt + (size_t)n * 4096 + qg * 8;
    lb[i] = Bs + c * 8;
  }

  const int w = t >> 6, lane = t & 63;
  const int wr = w >> 1, wc = w & 1;
  const int lq = lane >> 4, ln = lane & 15;

  f32x4 acc[4][4];
#pragma unroll
  for (int a = 0; a < 4; ++a)
#pragma unroll
    for (int b = 0; b < 4; ++b) acc[a][b] = (f32x4){0.f, 0.f, 0.f, 0.f};

  for (int k0 = 0; k0 < 4096; k0 += 32) {
    __syncthreads();                       // protect LDS being read
    if (k0 < 2048) {
#pragma unroll
      for (int i = 0; i < 4; ++i) g2lds16(gax[i] + k0, la[i]);
    } else {
#pragma unroll
      for (int i = 0; i < 4; ++i) g2lds16(gah[i] + (k0 - 2048), la[i]);
    }
#pragma unroll
    for (int i = 0; i < 2; ++i) g2lds16(gb[i] + k0, lb[i]);
    __syncthreads();                       // drains vmcnt -> staged data visible

    // A frags: A[m=lane&15][k=lq*8+j], fp32 chunks (lq*2, lq*2+1) at swizzled pos
    bf16x8 af[4], bv[4];
#pragma unroll
    for (int tm = 0; tm < 4; ++tm) {
      const int m = wr * 64 + tm * 16 + ln;
      const f32x4 f0 = *(const f32x4*)(As + m * 32 + ((lq * 2)     ^ (m & 7)) * 4);
      const f32x4 f1 = *(const f32x4*)(As + m * 32 + ((lq * 2 + 1) ^ (m & 7)) * 4);
      bf16x8 v;
      v[0] = f2bs(f0[0]); v[1] = f2bs(f0[1]); v[2] = f2bs(f0[2]); v[3] = f2bs(f0[3]);
      v[4] = f2bs(f1[0]); v[5] = f2bs(f1[1]); v[6] = f2bs(f1[2]); v[7] = f2bs(f1[3]);
      af[tm] = v;
    }
    // B frags: B[k=lq*8+j][n=lane&15], row = g*32 + wc*16 + ln, chunk lq at swizzled pos
#pragma unroll
    for (int g = 0; g < 4; ++g) {
      const int row = g * 32 + wc * 16 + ln;
      bv[g] = *(const bf16x8*)(Bs + row * 32 + (lq ^ ((row >> 1) & 3)) * 8);
    }
#pragma unroll
    for (int tm = 0; tm < 4; ++tm)
#pragma unroll
      for (int g = 0; g < 4; ++g)
        acc[tm][g] = __builtin_amdgcn_mfma_f32_16x16x32_bf16(af[tm], bv[g],
                                                             acc[tm][g], 0, 0, 0);
  }

  // Epilogue: C/D layout col=lane&15 (=j), row=lq*4+reg.
  const int jg = j0 + wc * 16 + ln;
  float bsum[4];
#pragma unroll
  for (int g = 0; g < 4; ++g)
    bsum[g] = bi[g * 2048 + jg] + bh[g * 2048 + jg];

#pragma unroll
  for (int tm = 0; tm < 4; ++tm) {
#pragma unroll
    for (int r = 0; r < 4; ++r) {
      const int m = m0 + wr * 64 + tm * 16 + lq * 4 + r;
      const size_t off = (size_t)m * 2048 + jg;
      const float fp = acc[tm][0][r] + bsum[0];
      const float ip = acc[tm][1][r] + bsum[1];
      const float gp = acc[tm][2][r] + bsum[2];
      const float op = acc[tm][3][r] + bsum[3];
      const float ft = 1.f / (1.f + __expf(-fp));
      const float it = 1.f / (1.f + __expf(-ip));
      const float gt = 1.f - 2.f / (1.f + __expf(2.f * gp));  // tanh, saturation-safe
      const float ot = 1.f / (1.f + __expf(-op));
      const float ct = ft * Cp[off] + it * gt;
      const float ht = ot * (1.f - 2.f / (1.f + __expf(2.f * ct)));
      out[off] = ht;                       // h_t (output 0)
      out[16777216 + off] = ht;            // h_t (output 1)
      out[33554432 + off] = ct;            // c_t (output 2)
    }
  }
}

extern "C" void kernel_launch(void* const* d_in, const int* in_sizes, int n_in,
                              void* d_out, int out_size, void* d_ws, size_t ws_size,
                              hipStream_t stream) {
  const float* X  = (const float*)d_in[0];
  const float* Hp = (const float*)d_in[1];
  const float* Cp = (const float*)d_in[2];
  const float* Wi = (const float*)d_in[3];
  const float* bi = (const float*)d_in[4];
  const float* Wh = (const float*)d_in[5];
  const float* bh = (const float*)d_in[6];
  float* out = (float*)d_out;
  __hip_bfloat16* Wt = (__hip_bfloat16*)d_ws;   // 8192*4096*2 = 64 MB

  transpose_w<<<dim3(256, 128), dim3(32, 8), 0, stream>>>(Wi, Wh, Wt);
  lstm_fused<<<dim3(64, 64), 256, 0, stream>>>(X, Hp, Cp, Wt, bi, bh, out);
}

// Round 3
// 1074.331 us; speedup vs baseline: 1.2645x; 1.2645x over previous
//
#include <hip/hip_runtime.h>
#include <hip/hip_bf16.h>
#include <stdint.h>

// LSTM cell, B=8192, IN=H=2048. Fused GEMM: M=8192, N=8192 (4 gates x 2048), K=4096.
// fp32 I/O, bf16 MFMA compute. Round 3: bf16-A pre-pass + 32x32x16 MFMA, 256x128 tile
// (2x FLOP per LDS byte vs round 2 -- round 2 was LDS-read-BW bound, MfmaUtil 21.5%).

typedef short bf16x8 __attribute__((ext_vector_type(8)));
typedef float f32x4 __attribute__((ext_vector_type(4)));
typedef float f32x16 __attribute__((ext_vector_type(16)));

typedef const __attribute__((address_space(1))) void* gptr_as1;
typedef __attribute__((address_space(3))) void* lptr_as3;

__device__ __forceinline__ void g2lds16(const void* g, void* l) {
  __builtin_amdgcn_global_load_lds((gptr_as1)g, (lptr_as3)l, 16, 0, 0);
}

__device__ __forceinline__ short f2bs(float x) {
  __hip_bfloat16 h = __float2bfloat16(x);  // RNE
  return *reinterpret_cast<short*>(&h);
}

// ---------------------------------------------------------------------------
// Wt[n][k] bf16: n gate-major [f,i,g,o] in [0,8192); k<2048 from Wi[k][n] fp32,
// else Wh[k-2048][n]. 64x64 tiles, float4 loads, 16B stores.
// ---------------------------------------------------------------------------
__global__ __launch_bounds__(256) void transpose_w(const float* __restrict__ Wi,
                                                   const float* __restrict__ Wh,
                                                   __hip_bfloat16* __restrict__ Wt) {
  __shared__ float tile[64][65];
  const int nt = blockIdx.x * 64;   // 128 blocks
  const int kt = blockIdx.y * 64;   // 64 blocks
  const float* src = (kt < 2048) ? (Wi + (size_t)kt * 8192)
                                 : (Wh + (size_t)(kt - 2048) * 8192);
  const int t = threadIdx.x;
#pragma unroll
  for (int i = 0; i < 4; ++i) {
    const int c = i * 256 + t;            // 0..1023
    const int kr = c >> 4, cc = c & 15;
    const float4 v = *(const float4*)(src + (size_t)kr * 8192 + nt + cc * 4);
    tile[kr][cc * 4 + 0] = v.x;
    tile[kr][cc * 4 + 1] = v.y;
    tile[kr][cc * 4 + 2] = v.z;
    tile[kr][cc * 4 + 3] = v.w;
  }
  __syncthreads();
#pragma unroll
  for (int i = 0; i < 2; ++i) {
    const int c = i * 256 + t;            // 0..511
    const int nr = c >> 3, ck = c & 7;
    bf16x8 o;
#pragma unroll
    for (int j = 0; j < 8; ++j) o[j] = f2bs(tile[ck * 8 + j][nr]);
    *(bf16x8*)(Wt + (size_t)(nt + nr) * 4096 + kt + ck * 8) = o;
  }
}

// ---------------------------------------------------------------------------
// Abf[m][k] bf16: k<2048 from X[m][k], else Hp[m][k-2048]. Streaming convert.
// ---------------------------------------------------------------------------
__global__ __launch_bounds__(256) void convert_a(const float* __restrict__ X,
                                                 const float* __restrict__ Hp,
                                                 __hip_bfloat16* __restrict__ Abf) {
  const int idx = blockIdx.x * 256 + threadIdx.x;   // [0, 8192*512)
  const int m = idx >> 9, g = idx & 511;
  const float* src = (g < 256) ? (X + (size_t)m * 2048 + g * 8)
                               : (Hp + (size_t)m * 2048 + (g - 256) * 8);
  const float4 a = *(const float4*)src;
  const float4 b = *(const float4*)(src + 4);
  bf16x8 o;
  o[0] = f2bs(a.x); o[1] = f2bs(a.y); o[2] = f2bs(a.z); o[3] = f2bs(a.w);
  o[4] = f2bs(b.x); o[5] = f2bs(b.y); o[6] = f2bs(b.z); o[7] = f2bs(b.w);
  *(bf16x8*)(Abf + (size_t)m * 4096 + g * 8) = o;
}

// ---------------------------------------------------------------------------
// Fast path: block tile 256(M) x 128(gathered N = 4 gates x 32 j), BK=32.
// 4 waves stacked in M; wave = 64 rows x 4 gate-tiles x 2 m-tiles of 32x32x16 MFMA.
// A/B operand: X[m=lane&31][k=(lane>>5)*8+j]; C/D (m74/m101): col=lane&31,
// row=(reg&3)+8*(reg>>2)+4*(lane>>5). Gate = tile index -> in-register epilogue.
// ---------------------------------------------------------------------------
__global__ __launch_bounds__(256, 2) void lstm_fused(
    const __hip_bfloat16* __restrict__ Abf,   // [8192][4096]
    const __hip_bfloat16* __restrict__ Wt,    // [8192][4096]
    const float* __restrict__ Cp,             // [8192][2048]
    const float* __restrict__ bi,             // [8192]
    const float* __restrict__ bh,             // [8192]
    float* __restrict__ out)                  // [3][8192][2048]
{
  __shared__ __align__(16) __hip_bfloat16 As[8192];  // [256 rows][4 chunks of 8]
  __shared__ __align__(16) __hip_bfloat16 Bs[4096];  // [128 rows][4 chunks of 8]
  const int t  = threadIdx.x;
  const int m0 = blockIdx.x * 256;
  const int j0 = blockIdx.y * 32;

  // staging: 16B chunks; row-major, chunk pos XOR-swizzled by (row&3) -> 2-way max
  const __hip_bfloat16* ga[4]; __hip_bfloat16* la[4];
#pragma unroll
  for (int i = 0; i < 4; ++i) {
    const int c = i * 256 + t;                 // A chunk 0..1023
    const int row = c >> 2, pos = c & 3, qg = pos ^ (row & 3);
    ga[i] = Abf + (size_t)(m0 + row) * 4096 + qg * 8;
    la[i] = As + c * 8;
  }
  const __hip_bfloat16* gb[2]; __hip_bfloat16* lb[2];
#pragma unroll
  for (int i = 0; i < 2; ++i) {
    const int c = i * 256 + t;                 // B chunk 0..511
    const int row = c >> 2, pos = c & 3, qg = pos ^ (row & 3);
    const int n = (row >> 5) * 2048 + j0 + (row & 31);  // gate-major W column
    gb[i] = Wt + (size_t)n * 4096 + qg * 8;
    lb[i] = Bs + c * 8;
  }

  const int w = t >> 6, lane = t & 63;
  const int lm = lane & 31, lk = lane >> 5;

  // loop-invariant LDS fragment offsets (bf16 elements)
  int aoff[2][2], boff[4][2];
#pragma unroll
  for (int tm = 0; tm < 2; ++tm) {
    const int ra = w * 64 + tm * 32 + lm;
#pragma unroll
    for (int kk = 0; kk < 2; ++kk)
      aoff[tm][kk] = ra * 32 + (((lk + 2 * kk)) ^ (ra & 3)) * 8;
  }
#pragma unroll
  for (int g = 0; g < 4; ++g) {
    const int rb = g * 32 + lm;
#pragma unroll
    for (int kk = 0; kk < 2; ++kk)
      boff[g][kk] = rb * 32 + (((lk + 2 * kk)) ^ (rb & 3)) * 8;
  }

  f32x16 acc[2][4];
#pragma unroll
  for (int a = 0; a < 2; ++a)
#pragma unroll
    for (int b = 0; b < 4; ++b)
#pragma unroll
      for (int r = 0; r < 16; ++r) acc[a][b][r] = 0.f;

  for (int k0 = 0; k0 < 4096; k0 += 32) {
    __syncthreads();
#pragma unroll
    for (int i = 0; i < 4; ++i) g2lds16(ga[i] + k0, la[i]);
#pragma unroll
    for (int i = 0; i < 2; ++i) g2lds16(gb[i] + k0, lb[i]);
    __syncthreads();
#pragma unroll
    for (int kk = 0; kk < 2; ++kk) {
      bf16x8 af[2], bv[4];
      af[0] = *(const bf16x8*)(As + aoff[0][kk]);
      af[1] = *(const bf16x8*)(As + aoff[1][kk]);
#pragma unroll
      for (int g = 0; g < 4; ++g) bv[g] = *(const bf16x8*)(Bs + boff[g][kk]);
#pragma unroll
      for (int tm = 0; tm < 2; ++tm)
#pragma unroll
        for (int g = 0; g < 4; ++g)
          acc[tm][g] = __builtin_amdgcn_mfma_f32_32x32x16_bf16(af[tm], bv[g],
                                                               acc[tm][g], 0, 0, 0);
    }
  }

  const int j = j0 + lm;
  float bsum[4];
#pragma unroll
  for (int g = 0; g < 4; ++g) bsum[g] = bi[g * 2048 + j] + bh[g * 2048 + j];

#pragma unroll
  for (int tm = 0; tm < 2; ++tm) {
#pragma unroll
    for (int r = 0; r < 16; ++r) {
      const int rowcd = (r & 3) + 8 * (r >> 2) + 4 * lk;
      const int m = m0 + w * 64 + tm * 32 + rowcd;
      const size_t off = (size_t)m * 2048 + j;
      const float fp = acc[tm][0][r] + bsum[0];
      const float ip = acc[tm][1][r] + bsum[1];
      const float gp = acc[tm][2][r] + bsum[2];
      const float op = acc[tm][3][r] + bsum[3];
      const float ft = 1.f / (1.f + __expf(-fp));
      const float it = 1.f / (1.f + __expf(-ip));
      const float gt = 1.f - 2.f / (1.f + __expf(2.f * gp));
      const float ot = 1.f / (1.f + __expf(-op));
      const float ct = ft * Cp[off] + it * gt;
      const float ht = ot * (1.f - 2.f / (1.f + __expf(2.f * ct)));
      out[off] = ht;
      out[16777216 + off] = ht;
      out[33554432 + off] = ct;
    }
  }
}

// ---------------------------------------------------------------------------
// Fallback (ws too small for Abf): round-2 kernel, fp32 A staged to LDS. PASSED.
// ---------------------------------------------------------------------------
__global__ __launch_bounds__(256) void lstm_fused_f32a(
    const float* __restrict__ X, const float* __restrict__ Hp,
    const float* __restrict__ Cp, const __hip_bfloat16* __restrict__ Wt,
    const float* __restrict__ bi, const float* __restrict__ bh,
    float* __restrict__ out)
{
  __shared__ __align__(16) float As[4096];
  __shared__ __align__(16) __hip_bfloat16 Bs[4096];
  const int t  = threadIdx.x;
  const int m0 = blockIdx.x * 128;
  const int j0 = blockIdx.y * 32;

  const float* gax[4]; const float* gah[4]; float* la[4];
#pragma unroll
  for (int i = 0; i < 4; ++i) {
    const int c = i * 256 + t;
    const int row = c >> 3, pos = c & 7;
    const int qg = pos ^ (row & 7);
    gax[i] = X  + (size_t)(m0 + row) * 2048 + qg * 4;
    gah[i] = Hp + (size_t)(m0 + row) * 2048 + qg * 4;
    la[i]  = As + c * 4;
  }
  const __hip_bfloat16* gb[2]; __hip_bfloat16* lb[2];
#pragma unroll
  for (int i = 0; i < 2; ++i) {
    const int c = i * 256 + t;
    const int row = c >> 2, pos = c & 3;
    const int qg = pos ^ ((row >> 1) & 3);
    const int n = (row >> 5) * 2048 + j0 + (row & 31);
    gb[i] = Wt + (size_t)n * 4096 + qg * 8;
    lb[i] = Bs + c * 8;
  }

  const int w = t >> 6, lane = t & 63;
  const int wr = w >> 1, wc = w & 1;
  const int lq = lane >> 4, ln = lane & 15;

  f32x4 acc[4][4];
#pragma unroll
  for (int a = 0; a < 4; ++a)
#pragma unroll
    for (int b = 0; b < 4; ++b) acc[a][b] = (f32x4){0.f, 0.f, 0.f, 0.f};

  for (int k0 = 0; k0 < 4096; k0 += 32) {
    __syncthreads();
    if (k0 < 2048) {
#pragma unroll
      for (int i = 0; i < 4; ++i) g2lds16(gax[i] + k0, la[i]);
    } else {
#pragma unroll
      for (int i = 0; i < 4; ++i) g2lds16(gah[i] + (k0 - 2048), la[i]);
    }
#pragma unroll
    for (int i = 0; i < 2; ++i) g2lds16(gb[i] + k0, lb[i]);
    __syncthreads();

    bf16x8 af[4], bv[4];
#pragma unroll
    for (int tm = 0; tm < 4; ++tm) {
      const int m = wr * 64 + tm * 16 + ln;
      const f32x4 f0 = *(const f32x4*)(As + m * 32 + ((lq * 2)     ^ (m & 7)) * 4);
      const f32x4 f1 = *(const f32x4*)(As + m * 32 + ((lq * 2 + 1) ^ (m & 7)) * 4);
      bf16x8 v;
      v[0] = f2bs(f0[0]); v[1] = f2bs(f0[1]); v[2] = f2bs(f0[2]); v[3] = f2bs(f0[3]);
      v[4] = f2bs(f1[0]); v[5] = f2bs(f1[1]); v[6] = f2bs(f1[2]); v[7] = f2bs(f1[3]);
      af[tm] = v;
    }
#pragma unroll
    for (int g = 0; g < 4; ++g) {
      const int row = g * 32 + wc * 16 + ln;
      bv[g] = *(const bf16x8*)(Bs + row * 32 + (lq ^ ((row >> 1) & 3)) * 8);
    }
#pragma unroll
    for (int tm = 0; tm < 4; ++tm)
#pragma unroll
      for (int g = 0; g < 4; ++g)
        acc[tm][g] = __builtin_amdgcn_mfma_f32_16x16x32_bf16(af[tm], bv[g],
                                                             acc[tm][g], 0, 0, 0);
  }

  const int jg = j0 + wc * 16 + ln;
  float bsum[4];
#pragma unroll
  for (int g = 0; g < 4; ++g) bsum[g] = bi[g * 2048 + jg] + bh[g * 2048 + jg];

#pragma unroll
  for (int tm = 0; tm < 4; ++tm) {
#pragma unroll
    for (int r = 0; r < 4; ++r) {
      const int m = m0 + wr * 64 + tm * 16 + lq * 4 + r;
      const size_t off = (size_t)m * 2048 + jg;
      const float fp = acc[tm][0][r] + bsum[0];
      const float ip = acc[tm][1][r] + bsum[1];
      const float gp = acc[tm][2][r] + bsum[2];
      const float op = acc[tm][3][r] + bsum[3];
      const float ft = 1.f / (1.f + __expf(-fp));
      const float it = 1.f / (1.f + __expf(-ip));
      const float gt = 1.f - 2.f / (1.f + __expf(2.f * gp));
      const float ot = 1.f / (1.f + __expf(-op));
      const float ct = ft * Cp[off] + it * gt;
      const float ht = ot * (1.f - 2.f / (1.f + __expf(2.f * ct)));
      out[off] = ht;
      out[16777216 + off] = ht;
      out[33554432 + off] = ct;
    }
  }
}

extern "C" void kernel_launch(void* const* d_in, const int* in_sizes, int n_in,
                              void* d_out, int out_size, void* d_ws, size_t ws_size,
                              hipStream_t stream) {
  const float* X  = (const float*)d_in[0];
  const float* Hp = (const float*)d_in[1];
  const float* Cp = (const float*)d_in[2];
  const float* Wi = (const float*)d_in[3];
  const float* bi = (const float*)d_in[4];
  const float* Wh = (const float*)d_in[5];
  const float* bh = (const float*)d_in[6];
  float* out = (float*)d_out;
  __hip_bfloat16* Wt = (__hip_bfloat16*)d_ws;          // 64 MB

  transpose_w<<<dim3(128, 64), dim3(256), 0, stream>>>(Wi, Wh, Wt);

  if (ws_size >= (size_t)134217728) {                  // 128 MB: Wt + Abf
    __hip_bfloat16* Abf = (__hip_bfloat16*)d_ws + 33554432;
    convert_a<<<16384, 256, 0, stream>>>(X, Hp, Abf);
    lstm_fused<<<dim3(32, 64), 256, 0, stream>>>(Abf, Wt, Cp, bi, bh, out);
  } else {
    lstm_fused_f32a<<<dim3(64, 64), 256, 0, stream>>>(X, Hp, Cp, Wt, bi, bh, out);
  }
}